// Round 3
// baseline (456.020 us; speedup 1.0000x reference)
//
#include <hip/hip_runtime.h>
#include <cstdint>
#include <cstddef>

#define EPSF 1e-7f
#define NCC 80
#define REG_MAX 16
#define TOPK 10
#define GRID_W 92
#define A_TOT (GRID_W * GRID_W)   // 8464
#define B_SZ 32
#define M_SZ 64

__device__ __forceinline__ float sigmoidf_(float x) { return 1.0f / (1.0f + expf(-x)); }

__device__ __forceinline__ float iou_xyxy(float gx1, float gy1, float gx2, float gy2,
                                          float px1, float py1, float px2, float py2) {
    float iw = fminf(gx2, px2) - fmaxf(gx1, px1); iw = fmaxf(iw, 0.f);
    float ih = fminf(gy2, py2) - fmaxf(gy1, py1); ih = fmaxf(ih, 0.f);
    float inter = iw * ih;
    float ag = (gx2 - gx1) * (gy2 - gy1);
    float ap = (px2 - px1) * (py2 - py1);
    return inter / (ag + ap - inter + EPSF);
}

// ------------------- Kernel A: per-(b,m) align metric + exact top-10 -------------------
__global__ __launch_bounds__(256) void kA(
    const float* __restrict__ ps,   // [B,A,NC]
    const float* __restrict__ pb,   // [B,A,4]
    const int*   __restrict__ gl,   // [B,M]
    const float* __restrict__ gb,   // [B,M,4]
    const float* __restrict__ mg,   // [B,M]
    const float* __restrict__ anc,  // [A,2]
    int*   __restrict__ cand_idx,   // [B*M*TOPK]
    float* __restrict__ cand_val,   // [B*M*TOPK]
    float* __restrict__ maxpg)      // [B*M]
{
    __shared__ float s_align[A_TOT];
    __shared__ float rv[256];
    __shared__ int   ri[256];
    __shared__ int   sel_idx[TOPK];
    __shared__ float sel_val[TOPK];
    __shared__ float s_keepval[TOPK];

    int bm = blockIdx.x;
    int b = bm / M_SZ;
    int t = threadIdx.x;
    float mgt = mg[bm];
    if (mgt <= 0.f) {
        if (t < TOPK) cand_idx[bm * TOPK + t] = -1;
        if (t == 0) maxpg[bm] = 0.f;
        return;
    }
    float gx1 = gb[bm * 4 + 0], gy1 = gb[bm * 4 + 1];
    float gx2 = gb[bm * 4 + 2], gy2 = gb[bm * 4 + 3];
    int cls = gl[bm]; cls = min(max(cls, 0), NCC - 1);
    const float* psb = ps + (size_t)b * A_TOT * NCC + cls;
    const float* pbb = pb + (size_t)b * A_TOT * 4;

    for (int a = t; a < A_TOT; a += 256) {
        float4 p = *(const float4*)(pbb + (size_t)a * 4);
        float iou = iou_xyxy(gx1, gy1, gx2, gy2, p.x, p.y, p.z, p.w);
        float sc  = sigmoidf_(psb[(size_t)a * NCC]);
        float i2 = iou * iou;
        s_align[a] = sqrtf(sc) * (i2 * i2 * i2);   // mgt == 1.0 here
    }
    __syncthreads();

    // 10 exact iterative max selections (ties -> smallest index, matches lax.top_k)
    for (int it = 0; it < TOPK; ++it) {
        float bv = -1.f; int bi = A_TOT;
        for (int a = t; a < A_TOT; a += 256) {
            float v = s_align[a];
            if (v > bv) { bv = v; bi = a; }
        }
        rv[t] = bv; ri[t] = bi;
        __syncthreads();
        for (int s = 128; s > 0; s >>= 1) {
            if (t < s) {
                float ov = rv[t + s]; int oi = ri[t + s];
                if (ov > rv[t] || (ov == rv[t] && oi < ri[t])) { rv[t] = ov; ri[t] = oi; }
            }
            __syncthreads();
        }
        if (t == 0) {
            sel_idx[it] = ri[0]; sel_val[it] = rv[0];
            s_align[ri[0]] = -1.f;
        }
        __syncthreads();
    }

    if (t < TOPK) {
        int a = sel_idx[t]; float v = sel_val[t];
        float ax = anc[(size_t)a * 2], ay = anc[(size_t)a * 2 + 1];
        float d1 = ax - gx1, d2 = ay - gy1, d3 = gx2 - ax, d4 = gy2 - ay;
        float dmin = fminf(fminf(d1, d2), fminf(d3, d4));
        bool keep = dmin > EPSF;
        cand_idx[bm * TOPK + t] = keep ? a : -1;
        cand_val[bm * TOPK + t] = v;
        s_keepval[t] = keep ? v : -1.f;
    }
    __syncthreads();
    if (t == 0) {
        float mx = 0.f;
        for (int i = 0; i < TOPK; ++i)
            if (s_keepval[i] >= 0.f) mx = fmaxf(mx, s_keepval[i]);
        maxpg[bm] = mx;
    }
}

// ------------------- Kernel B: scatter candidates -> per-anchor argmax key -------------------
__global__ void kB(const int* __restrict__ cand_idx, const float* __restrict__ cand_val,
                   unsigned long long* __restrict__ key)
{
    int i = blockIdx.x * blockDim.x + threadIdx.x;
    if (i >= B_SZ * M_SZ * TOPK) return;
    int a = cand_idx[i];
    if (a < 0) return;
    int bm = i / TOPK;
    int b = bm / M_SZ, m = bm % M_SZ;
    float v = cand_val[i];
    unsigned long long k = ((unsigned long long)__float_as_uint(v) << 32)
                         | (unsigned long long)(0xFFFFu - (unsigned)m);
    atomicMax(&key[(size_t)b * A_TOT + a], k);
}

// ------------------- Kernel C: per-fg-anchor loss terms -------------------
__global__ __launch_bounds__(256) void kC(
    const float* __restrict__ ps, const float* __restrict__ pd, const float* __restrict__ pb,
    const float* __restrict__ anc, const int* __restrict__ gl, const float* __restrict__ gb,
    const float* __restrict__ mg, const unsigned long long* __restrict__ key,
    const float* __restrict__ maxpg, double* __restrict__ acc)
{
    int i = blockIdx.x * blockDim.x + threadIdx.x;
    double s1 = 0, s2 = 0, s3 = 0, s4 = 0, nf = 0;
    if (i < B_SZ * A_TOT) {
        unsigned long long k = key[i];
        if (k) {
            int b = i / A_TOT, a = i % A_TOT;
            unsigned vbits = (unsigned)(k >> 32);
            int m = vbits ? (int)(0xFFFFu - (unsigned)(k & 0xFFFFull)) : 0;
            int bm = b * M_SZ + m;
            float gx1 = gb[bm * 4 + 0], gy1 = gb[bm * 4 + 1];
            float gx2 = gb[bm * 4 + 2], gy2 = gb[bm * 4 + 3];
            int cls = min(max(gl[bm], 0), NCC - 1);
            float mgt = mg[bm];
            const float* px = pb + ((size_t)b * A_TOT + a) * 4;
            float p1 = px[0], p2 = px[1], p3 = px[2], p4 = px[3];

            // recomputed align metric (exactly matches ref incl. degenerate tgi=0)
            float iou_a = iou_xyxy(gx1, gy1, gx2, gy2, p1, p2, p3, p4);
            float xt = ps[((size_t)b * A_TOT + a) * NCC + cls];
            float sc = sigmoidf_(xt);
            float i2 = iou_a * iou_a;
            float align = sqrtf(sc) * (i2 * i2 * i2) * mgt;
            float norm = align / (maxpg[bm] + EPSF);

            // CIoU(pred, tbox)
            float iw = fmaxf(fminf(p3, gx2) - fmaxf(p1, gx1), 0.f);
            float ih = fmaxf(fminf(p4, gy2) - fmaxf(p2, gy1), 0.f);
            float inter = iw * ih;
            float a1 = (p3 - p1) * (p4 - p2);
            float a2 = (gx2 - gx1) * (gy2 - gy1);
            float iou = inter / (a1 + a2 - inter + EPSF);
            float cw = fmaxf(p3, gx2) - fminf(p1, gx1);
            float ch = fmaxf(p4, gy2) - fminf(p2, gy1);
            float c2 = cw * cw + ch * ch + EPSF;
            float dx = p1 + p3 - gx1 - gx2, dy = p2 + p4 - gy1 - gy2;
            float rho2 = (dx * dx + dy * dy) * 0.25f;
            float w1 = p3 - p1, h1 = p4 - p2;
            float w2 = gx2 - gx1, h2 = gy2 - gy1;
            float dat = atanf(w1 / (h1 + EPSF)) - atanf(w2 / (h2 + EPSF));
            const float c4pi2 = (float)(4.0 / (3.14159265358979323846 * 3.14159265358979323846));
            float v = c4pi2 * dat * dat;
            float alpha = v / (1.f - iou + v + EPSF);
            float ciou = iou - (rho2 / c2 + v * alpha);

            // DFL
            float ax = anc[(size_t)a * 2], ay = anc[(size_t)a * 2 + 1];
            float tv[4] = { ax - gx1, ay - gy1, gx2 - ax, gy2 - ay };
            const float* pdd = pd + ((size_t)b * A_TOT + a) * 64;
            float dfl = 0.f;
            #pragma unroll
            for (int s = 0; s < 4; ++s) {
                float tt = fminf(fmaxf(tv[s], 0.f), (float)REG_MAX - 1.f - 0.01f);
                int tl = (int)tt;
                int tr = min(tl + 1, REG_MAX - 1);
                float wl = (float)(tl + 1) - tt;
                float wr = 1.f - wl;
                const float* row = pdd + s * 16;
                float mx = row[0];
                #pragma unroll
                for (int kk = 1; kk < 16; ++kk) mx = fmaxf(mx, row[kk]);
                float se = 0.f;
                #pragma unroll
                for (int kk = 0; kk < 16; ++kk) se += expf(row[kk] - mx);
                float lse = mx + logf(se);
                dfl += (lse - row[tl]) * wl + (lse - row[tr]) * wr;
            }

            s1 = (double)norm;
            s2 = (double)xt * (double)norm;
            s3 = (double)(1.f - ciou) * (double)norm;
            s4 = (double)dfl;
            nf = 1.0;
        }
    }
    __shared__ double sred[256];
    double vals[5] = { s1, s2, s3, s4, nf };
    for (int j = 0; j < 5; ++j) {
        sred[threadIdx.x] = vals[j];
        __syncthreads();
        for (int s = 128; s > 0; s >>= 1) {
            if (threadIdx.x < s) sred[threadIdx.x] += sred[threadIdx.x + s];
            __syncthreads();
        }
        if (threadIdx.x == 0 && sred[0] != 0.0) atomicAdd(&acc[j], sred[0]);
        __syncthreads();
    }
}

// ------------------- Kernel D: BCE constant term over full score tensor -------------------
__device__ __forceinline__ float bce_const(float x) {
    return fmaxf(x, 0.f) + log1pf(expf(-fabsf(x)));
}

__global__ __launch_bounds__(256) void kD(const float* __restrict__ ps, double* __restrict__ acc)
{
    const size_t n = (size_t)B_SZ * A_TOT * NCC;   // divisible by 4
    size_t i = ((size_t)blockIdx.x * blockDim.x + threadIdx.x) * 4;
    size_t stride = (size_t)gridDim.x * blockDim.x * 4;
    double s = 0;
    for (; i < n; i += stride) {
        float4 x = *(const float4*)(ps + i);
        s += (double)(bce_const(x.x) + bce_const(x.y) + bce_const(x.z) + bce_const(x.w));
    }
    __shared__ double sred[256];
    sred[threadIdx.x] = s;
    __syncthreads();
    for (int st = 128; st > 0; st >>= 1) {
        if (threadIdx.x < st) sred[threadIdx.x] += sred[threadIdx.x + st];
        __syncthreads();
    }
    if (threadIdx.x == 0) atomicAdd(&acc[5], sred[0]);
}

// ------------------- Kernel E: combine -------------------
__global__ void kE(const double* __restrict__ acc, float* __restrict__ out)
{
    double tsum = acc[0];
    double tss = tsum > 1.0 ? tsum : 1.0;
    double bce = acc[5] - acc[1];
    double loss_cls = bce / tss;
    double loss_iou = acc[2] / tss;
    double nf = acc[4];
    double loss_dfl = (nf > 0.0) ? acc[3] / fmax(4.0 * nf, 1.0) : 0.0;
    out[0] = (float)(7.5 * loss_iou + 0.5 * loss_cls + 1.5 * loss_dfl);
}

extern "C" void kernel_launch(void* const* d_in, const int* in_sizes, int n_in,
                              void* d_out, int out_size, void* d_ws, size_t ws_size,
                              hipStream_t stream)
{
    const float* ps  = (const float*)d_in[0];   // pred_scores  [B,A,NC]
    const float* pd  = (const float*)d_in[1];   // pred_dist    [B,A,64]
    const float* pb  = (const float*)d_in[2];   // pred_bboxes  [B,A,4]
    const float* anc = (const float*)d_in[3];   // anchor_points [A,2]
    const int*   gl  = (const int*)d_in[4];     // gt_labels    [B,M]
    const float* gb  = (const float*)d_in[5];   // gt_bboxes    [B,M,4]
    const float* mg  = (const float*)d_in[6];   // mask_gt      [B,M]
    float* out = (float*)d_out;

    char* ws = (char*)d_ws;
    const size_t key_bytes = (size_t)B_SZ * A_TOT * sizeof(unsigned long long); // 2,166,784
    unsigned long long* key = (unsigned long long*)ws;
    double* acc       = (double*)(ws + key_bytes);                    // 8 doubles
    int*    cand_idx  = (int*)  (ws + key_bytes + 64);
    float*  cand_val  = (float*)(ws + key_bytes + 64 + (size_t)B_SZ * M_SZ * TOPK * 4);
    float*  maxpg     = (float*)(ws + key_bytes + 64 + (size_t)B_SZ * M_SZ * TOPK * 8);

    // zero key + accumulators (cand_* / maxpg fully overwritten by kA)
    hipMemsetAsync(ws, 0, key_bytes + 64, stream);

    kA<<<B_SZ * M_SZ, 256, 0, stream>>>(ps, pb, gl, gb, mg, anc, cand_idx, cand_val, maxpg);
    kB<<<(B_SZ * M_SZ * TOPK + 255) / 256, 256, 0, stream>>>(cand_idx, cand_val, key);
    kC<<<(B_SZ * A_TOT + 255) / 256, 256, 0, stream>>>(ps, pd, pb, anc, gl, gb, mg, key, maxpg, acc);
    kD<<<2048, 256, 0, stream>>>(ps, acc);
    kE<<<1, 1, 0, stream>>>(acc, out);
}

// Round 7
// 376.586 us; speedup vs baseline: 1.2109x; 1.2109x over previous
//
#include <hip/hip_runtime.h>
#include <cstdint>
#include <cstddef>

#define EPSF 1e-7f
#define NCC 80
#define REG_MAX 16
#define TOPK 10
#define GRID_W 92
#define A_TOT (GRID_W * GRID_W)   // 8464
#define B_SZ 32
#define M_SZ 64
#define CHUNK 64
#define NCHUNK ((A_TOT + CHUNK - 1) / CHUNK)   // 133

__device__ __forceinline__ float sigmoidf_(float x) { return 1.0f / (1.0f + expf(-x)); }

__device__ __forceinline__ float iou_xyxy(float gx1, float gy1, float gx2, float gy2,
                                          float px1, float py1, float px2, float py2) {
    float iw = fminf(gx2, px2) - fmaxf(gx1, px1); iw = fmaxf(iw, 0.f);
    float ih = fminf(gy2, py2) - fmaxf(gy1, py1); ih = fmaxf(ih, 0.f);
    float inter = iw * ih;
    float ag = (gx2 - gx1) * (gy2 - gy1);
    float ap = (px2 - px1) * (py2 - py1);
    return inter / (ag + ap - inter + EPSF);
}

__device__ __forceinline__ float bce_const(float x) {
    return fmaxf(x, 0.f) + log1pf(expf(-fabsf(x)));
}

// ---------- kP: coalesced pass over pred_scores -> {BCE sum, align tensor} ----------
// block = 256 threads <-> 64 anchors of one batch image; wave w handles m in [16w,16w+16)
__global__ __launch_bounds__(256) void kP(
    const float* __restrict__ ps,   // [B,A,NC]
    const float* __restrict__ pb,   // [B,A,4]
    const int*   __restrict__ gl,   // [B,M]
    const float* __restrict__ gb,   // [B,M,4]
    const float* __restrict__ mg,   // [B,M]
    float* __restrict__ align_t,    // [B,M,A]
    double* __restrict__ acc)
{
    __shared__ float  sq[CHUNK][NCC + 1];   // +1 pad: column reads hit all banks
    __shared__ float  sgb[M_SZ][4];
    __shared__ int    scls[M_SZ];
    __shared__ float  smg[M_SZ];
    __shared__ double sred[256];

    int blk = blockIdx.x;
    int b = blk / NCHUNK;
    int chunk = blk % NCHUNK;
    int a0 = chunk * CHUNK;
    int t = threadIdx.x;

    if (t < M_SZ) {
        int bm = b * M_SZ + t;
        float4 g = *(const float4*)(gb + (size_t)bm * 4);
        sgb[t][0] = g.x; sgb[t][1] = g.y; sgb[t][2] = g.z; sgb[t][3] = g.w;
        int c = gl[bm]; scls[t] = min(max(c, 0), NCC - 1);
        smg[t] = mg[bm];
    }

    // stage 64 rows x 80 floats (contiguous 20 KB region), fully coalesced float4
    const float* base = ps + ((size_t)b * A_TOT + a0) * NCC;
    double bces = 0.0;
    #pragma unroll
    for (int k = 0; k < 5; ++k) {
        int q = t + k * 256;          // float4 index within chunk; 80%4==0 so no row-cross
        int r = q / 20;
        int c = (q % 20) * 4;
        if (a0 + r < A_TOT) {
            float4 v = *(const float4*)(base + (size_t)r * NCC + c);
            bces += (double)(bce_const(v.x) + bce_const(v.y) + bce_const(v.z) + bce_const(v.w));
            sq[r][c]     = sqrtf(sigmoidf_(v.x));
            sq[r][c + 1] = sqrtf(sigmoidf_(v.y));
            sq[r][c + 2] = sqrtf(sigmoidf_(v.z));
            sq[r][c + 3] = sqrtf(sigmoidf_(v.w));
        }
    }
    __syncthreads();

    int w = t >> 6, l = t & 63;
    int a = a0 + l;
    if (a < A_TOT) {
        float4 p = *(const float4*)(pb + ((size_t)b * A_TOT + a) * 4);
        #pragma unroll
        for (int mi = 0; mi < 16; ++mi) {
            int m = w * 16 + mi;
            float iou = iou_xyxy(sgb[m][0], sgb[m][1], sgb[m][2], sgb[m][3],
                                 p.x, p.y, p.z, p.w);
            float s = sq[l][scls[m]];
            float i2 = iou * iou;
            // identical arithmetic order to round-3 kA (absmax was 0.0); smg in {0,1} exact
            align_t[((size_t)(b * M_SZ + m)) * A_TOT + a] = smg[m] * (s * (i2 * i2 * i2));
        }
    }

    sred[t] = bces;
    __syncthreads();
    for (int st = 128; st > 0; st >>= 1) {
        if (t < st) sred[t] += sred[t + st];
        __syncthreads();
    }
    if (t == 0) atomicAdd(&acc[5], sred[0]);
}

// ---------- kA2: exact top-10 per (b,m) from precomputed align row + scatter ----------
__global__ __launch_bounds__(256) void kA2(
    const float* __restrict__ align_t,  // [B,M,A]
    const float* __restrict__ gb,       // [B,M,4]
    const float* __restrict__ mg,       // [B,M]
    const float* __restrict__ anc,      // [A,2]
    unsigned long long* __restrict__ key,  // [B,A]
    float* __restrict__ maxpg)          // [B*M]
{
    __shared__ float s_align[A_TOT];
    __shared__ float wv[4];
    __shared__ int   wi[4];
    __shared__ int   sel_idx[TOPK];
    __shared__ float sel_val[TOPK];
    __shared__ float s_keepval[TOPK];

    int bm = blockIdx.x;
    int t = threadIdx.x;
    float mgt = mg[bm];
    if (mgt <= 0.f) {
        if (t == 0) maxpg[bm] = 0.f;
        return;
    }

    const float4* src = (const float4*)(align_t + (size_t)bm * A_TOT);
    float4* dst = (float4*)s_align;
    for (int q = t; q < A_TOT / 4; q += 256) dst[q] = src[q];
    __syncthreads();

    for (int it = 0; it < TOPK; ++it) {
        float bv = -1.f; int bi = A_TOT;
        for (int a = t; a < A_TOT; a += 256) {
            float v = s_align[a];
            if (v > bv) { bv = v; bi = a; }
        }
        // wave butterfly reduce (val desc, idx asc) — associative, exact ties
        #pragma unroll
        for (int off = 1; off < 64; off <<= 1) {
            float ov = __shfl_xor(bv, off);
            int   oi = __shfl_xor(bi, off);
            if (ov > bv || (ov == bv && oi < bi)) { bv = ov; bi = oi; }
        }
        if ((t & 63) == 0) { wv[t >> 6] = bv; wi[t >> 6] = bi; }
        __syncthreads();
        if (t == 0) {
            float fv = wv[0]; int fi = wi[0];
            #pragma unroll
            for (int j = 1; j < 4; ++j) {
                float ov = wv[j]; int oi = wi[j];
                if (ov > fv || (ov == fv && oi < fi)) { fv = ov; fi = oi; }
            }
            sel_idx[it] = fi; sel_val[it] = fv;
            s_align[fi] = -1.f;
        }
        __syncthreads();
    }

    if (t < TOPK) {
        int a = sel_idx[t]; float v = sel_val[t];
        float gx1 = gb[bm * 4 + 0], gy1 = gb[bm * 4 + 1];
        float gx2 = gb[bm * 4 + 2], gy2 = gb[bm * 4 + 3];
        float ax = anc[(size_t)a * 2], ay = anc[(size_t)a * 2 + 1];
        float d1 = ax - gx1, d2 = ay - gy1, d3 = gx2 - ax, d4 = gy2 - ay;
        float dmin = fminf(fminf(d1, d2), fminf(d3, d4));
        bool keep = dmin > EPSF;
        s_keepval[t] = keep ? v : -1.f;
        if (keep) {
            int b = bm / M_SZ, m = bm % M_SZ;
            unsigned long long k = ((unsigned long long)__float_as_uint(v) << 32)
                                 | (unsigned long long)(0xFFFFu - (unsigned)m);
            atomicMax(&key[(size_t)b * A_TOT + a], k);
        }
    }
    __syncthreads();
    if (t == 0) {
        float mx = 0.f;
        for (int i = 0; i < TOPK; ++i)
            if (s_keepval[i] >= 0.f) mx = fmaxf(mx, s_keepval[i]);
        maxpg[bm] = mx;
    }
}

// ---------- kC: per-fg-anchor loss terms (reads align tensor) ----------
__global__ __launch_bounds__(256) void kC(
    const float* __restrict__ ps, const float* __restrict__ pd, const float* __restrict__ pb,
    const float* __restrict__ anc, const int* __restrict__ gl, const float* __restrict__ gb,
    const float* __restrict__ align_t, const unsigned long long* __restrict__ key,
    const float* __restrict__ maxpg, double* __restrict__ acc)
{
    int i = blockIdx.x * blockDim.x + threadIdx.x;
    double s1 = 0, s2 = 0, s3 = 0, s4 = 0, nf = 0;
    if (i < B_SZ * A_TOT) {
        unsigned long long k = key[i];
        if (k) {
            int b = i / A_TOT, a = i % A_TOT;
            unsigned vbits = (unsigned)(k >> 32);
            int m = vbits ? (int)(0xFFFFu - (unsigned)(k & 0xFFFFull)) : 0;
            int bm = b * M_SZ + m;
            float gx1 = gb[bm * 4 + 0], gy1 = gb[bm * 4 + 1];
            float gx2 = gb[bm * 4 + 2], gy2 = gb[bm * 4 + 3];
            int cls = min(max(gl[bm], 0), NCC - 1);
            const float* px = pb + ((size_t)b * A_TOT + a) * 4;
            float p1 = px[0], p2 = px[1], p3 = px[2], p4 = px[3];

            float av = align_t[(size_t)bm * A_TOT + a];
            float xt = ps[((size_t)b * A_TOT + a) * NCC + cls];
            float norm = av / (maxpg[bm] + EPSF);

            // CIoU(pred, tbox)
            float iw = fmaxf(fminf(p3, gx2) - fmaxf(p1, gx1), 0.f);
            float ih = fmaxf(fminf(p4, gy2) - fmaxf(p2, gy1), 0.f);
            float inter = iw * ih;
            float a1 = (p3 - p1) * (p4 - p2);
            float a2 = (gx2 - gx1) * (gy2 - gy1);
            float iou = inter / (a1 + a2 - inter + EPSF);
            float cw = fmaxf(p3, gx2) - fminf(p1, gx1);
            float ch = fmaxf(p4, gy2) - fminf(p2, gy1);
            float c2 = cw * cw + ch * ch + EPSF;
            float dx = p1 + p3 - gx1 - gx2, dy = p2 + p4 - gy1 - gy2;
            float rho2 = (dx * dx + dy * dy) * 0.25f;
            float w1 = p3 - p1, h1 = p4 - p2;
            float w2 = gx2 - gx1, h2 = gy2 - gy1;
            float dat = atanf(w1 / (h1 + EPSF)) - atanf(w2 / (h2 + EPSF));
            const float c4pi2 = (float)(4.0 / (3.14159265358979323846 * 3.14159265358979323846));
            float v = c4pi2 * dat * dat;
            float alpha = v / (1.f - iou + v + EPSF);
            float ciou = iou - (rho2 / c2 + v * alpha);

            // DFL
            float ax = anc[(size_t)a * 2], ay = anc[(size_t)a * 2 + 1];
            float tv[4] = { ax - gx1, ay - gy1, gx2 - ax, gy2 - ay };
            const float* pdd = pd + ((size_t)b * A_TOT + a) * 64;
            float dfl = 0.f;
            #pragma unroll
            for (int s = 0; s < 4; ++s) {
                float tt = fminf(fmaxf(tv[s], 0.f), (float)REG_MAX - 1.f - 0.01f);
                int tl = (int)tt;
                int tr = min(tl + 1, REG_MAX - 1);
                float wl = (float)(tl + 1) - tt;
                float wr = 1.f - wl;
                const float* row = pdd + s * 16;
                float mx = row[0];
                #pragma unroll
                for (int kk = 1; kk < 16; ++kk) mx = fmaxf(mx, row[kk]);
                float se = 0.f;
                #pragma unroll
                for (int kk = 0; kk < 16; ++kk) se += expf(row[kk] - mx);
                float lse = mx + logf(se);
                dfl += (lse - row[tl]) * wl + (lse - row[tr]) * wr;
            }

            s1 = (double)norm;
            s2 = (double)xt * (double)norm;
            s3 = (double)(1.f - ciou) * (double)norm;
            s4 = (double)dfl;
            nf = 1.0;
        }
    }
    __shared__ double sred[256];
    double vals[5] = { s1, s2, s3, s4, nf };
    for (int j = 0; j < 5; ++j) {
        sred[threadIdx.x] = vals[j];
        __syncthreads();
        for (int s = 128; s > 0; s >>= 1) {
            if (threadIdx.x < s) sred[threadIdx.x] += sred[threadIdx.x + s];
            __syncthreads();
        }
        if (threadIdx.x == 0 && sred[0] != 0.0) atomicAdd(&acc[j], sred[0]);
        __syncthreads();
    }
}

// ---------- kE: combine ----------
__global__ void kE(const double* __restrict__ acc, float* __restrict__ out)
{
    double tsum = acc[0];
    double tss = tsum > 1.0 ? tsum : 1.0;
    double bce = acc[5] - acc[1];
    double loss_cls = bce / tss;
    double loss_iou = acc[2] / tss;
    double nf = acc[4];
    double loss_dfl = (nf > 0.0) ? acc[3] / fmax(4.0 * nf, 1.0) : 0.0;
    out[0] = (float)(7.5 * loss_iou + 0.5 * loss_cls + 1.5 * loss_dfl);
}

extern "C" void kernel_launch(void* const* d_in, const int* in_sizes, int n_in,
                              void* d_out, int out_size, void* d_ws, size_t ws_size,
                              hipStream_t stream)
{
    const float* ps  = (const float*)d_in[0];   // pred_scores  [B,A,NC]
    const float* pd  = (const float*)d_in[1];   // pred_dist    [B,A,64]
    const float* pb  = (const float*)d_in[2];   // pred_bboxes  [B,A,4]
    const float* anc = (const float*)d_in[3];   // anchor_points [A,2]
    const int*   gl  = (const int*)d_in[4];     // gt_labels    [B,M]
    const float* gb  = (const float*)d_in[5];   // gt_bboxes    [B,M,4]
    const float* mg  = (const float*)d_in[6];   // mask_gt      [B,M]
    float* out = (float*)d_out;

    char* ws = (char*)d_ws;
    const size_t align_bytes = (size_t)B_SZ * M_SZ * A_TOT * sizeof(float);        // 69,337,088
    const size_t key_bytes   = (size_t)B_SZ * A_TOT * sizeof(unsigned long long);  //  2,166,784
    float*              align_t = (float*)ws;
    unsigned long long* key     = (unsigned long long*)(ws + align_bytes);
    double*             acc     = (double*)(ws + align_bytes + key_bytes);         // 8 doubles
    float*              maxpg   = (float*)(ws + align_bytes + key_bytes + 64);

    // zero key + accumulators (align/maxpg fully overwritten)
    hipMemsetAsync(ws + align_bytes, 0, key_bytes + 64, stream);

    kP <<<B_SZ * NCHUNK, 256, 0, stream>>>(ps, pb, gl, gb, mg, align_t, acc);
    kA2<<<B_SZ * M_SZ,   256, 0, stream>>>(align_t, gb, mg, anc, key, maxpg);
    kC <<<(B_SZ * A_TOT + 255) / 256, 256, 0, stream>>>(ps, pd, pb, anc, gl, gb, align_t, key, maxpg, acc);
    kE <<<1, 1, 0, stream>>>(acc, out);
}

// Round 10
// 318.043 us; speedup vs baseline: 1.4338x; 1.1841x over previous
//
#include <hip/hip_runtime.h>
#include <cstdint>
#include <cstddef>

#define EPSF 1e-7f
#define NCC 80
#define REG_MAX 16
#define TOPK 10
#define GRID_W 92
#define A_TOT (GRID_W * GRID_W)   // 8464
#define B_SZ 32
#define M_SZ 64
#define CHUNK 64
#define NCHUNK ((A_TOT + CHUNK - 1) / CHUNK)   // 133
#define WMAX 52                    // max window rows/cols: (int)h(<24)+27 <= 51

// exact div-by-92 for a in [0, 8464): (a*45591)>>22
__device__ __forceinline__ int div92(int a) { return (a * 45591) >> 22; }

// ---------- kP: coalesced pass over pred_scores -> {BCE sum, windowed align tensor} ----------
__global__ __launch_bounds__(256) void kP(
    const float* __restrict__ ps,   // [B,A,NC]
    const float* __restrict__ pb,   // [B,A,4]
    const int*   __restrict__ gl,   // [B,M]
    const float* __restrict__ gb,   // [B,M,4]
    const float* __restrict__ mg,   // [B,M]
    float* __restrict__ align_t,    // [B,M,A] (written only for window-row chunks)
    double* __restrict__ acc)
{
    __shared__ float  sq[CHUNK][NCC + 1];   // sigmoid values; +1 pad
    __shared__ float  sgb[M_SZ][4];
    __shared__ float  sag[M_SZ];
    __shared__ int    scls[M_SZ];
    __shared__ int    swy[M_SZ];            // wy0 | wy1<<8 (empty=1|0 when mg==0)
    __shared__ double sred[256];

    int blk = blockIdx.x;
    int b = blk / NCHUNK;
    int chunk = blk % NCHUNK;
    int a0 = chunk * CHUNK;
    int t = threadIdx.x;

    if (t < M_SZ) {
        int bm = b * M_SZ + t;
        float4 g = *(const float4*)(gb + (size_t)bm * 4);
        sgb[t][0] = g.x; sgb[t][1] = g.y; sgb[t][2] = g.z; sgb[t][3] = g.w;
        sag[t] = (g.z - g.x) * (g.w - g.y);
        int c = gl[bm]; scls[t] = min(max(c, 0), NCC - 1);
        int y0, y1;
        if (mg[bm] > 0.f) { y0 = max(0, (int)g.y - 13); y1 = min(91, (int)g.w + 13); }
        else             { y0 = 1; y1 = 0; }           // empty window
        swy[t] = y0 | (y1 << 8);
    }

    // stage 64 rows x 80 floats, coalesced float4; fused BCE-const sum (fast math)
    const float* base = ps + ((size_t)b * A_TOT + a0) * NCC;
    double bces = 0.0;
    #pragma unroll
    for (int k = 0; k < 5; ++k) {
        int q = t + k * 256;          // 80%4==0: no row-cross
        int r = q / 20;
        int c = (q % 20) * 4;
        if (a0 + r < A_TOT) {
            float4 v = *(const float4*)(base + (size_t)r * NCC + c);
            float bsum = 0.f;
            #pragma unroll
            for (int j = 0; j < 4; ++j) {
                float x = (&v.x)[j];
                float t1 = __expf(-fabsf(x));
                bsum += fmaxf(x, 0.f) + __logf(1.f + t1);
                float rin = __fdividef(1.f, 1.f + t1);
                sq[r][c + j] = (x >= 0.f) ? rin : t1 * rin;   // sigmoid via exp reuse
            }
            bces += (double)bsum;
        }
    }
    __syncthreads();

    int w = t >> 6, l = t & 63;
    int a = a0 + l;
    int cgy0 = a0 / GRID_W, cgy1 = (a0 + 63) / GRID_W;   // chunk row span (uniform)
    if (a < A_TOT) {
        float4 p = *(const float4*)(pb + ((size_t)b * A_TOT + a) * 4);
        float ap_area = (p.z - p.x) * (p.w - p.y);
        float* outbase = align_t + (size_t)b * M_SZ * A_TOT + a;
        #pragma unroll
        for (int mi = 0; mi < 16; ++mi) {
            int m = w * 16 + mi;
            int wyp = swy[m];
            int y0 = wyp & 0xFF, y1 = (wyp >> 8) & 0xFF;
            if (cgy1 < y0 || cgy0 > y1) continue;   // wave-uniform skip: align==0 there, never read
            float g1 = sgb[m][0], g2 = sgb[m][1], g3 = sgb[m][2], g4 = sgb[m][3];
            float iw = fmaxf(fminf(g3, p.z) - fmaxf(g1, p.x), 0.f);
            float ih = fmaxf(fminf(g4, p.w) - fmaxf(g2, p.y), 0.f);
            float inter = iw * ih;
            float iou = inter * __fdividef(1.f, sag[m] + ap_area - inter + EPSF);
            float s = sqrtf(sq[l][scls[m]]);
            float i2 = iou * iou;
            outbase[(size_t)m * A_TOT] = s * (i2 * i2 * i2);  // mg>0 here => mask factor == 1
        }
    }

    sred[t] = bces;
    __syncthreads();
    for (int st = 128; st > 0; st >>= 1) {
        if (t < st) sred[t] += sred[t + st];
        __syncthreads();
    }
    if (t == 0) atomicAdd(&acc[5], sred[0]);
}

// ---------- kA3: windowed exact top-10 per (b,m), one wave per block ----------
__global__ __launch_bounds__(64) void kA3(
    const float* __restrict__ align_t,
    const float* __restrict__ gb,
    const float* __restrict__ mg,
    unsigned long long* __restrict__ key,   // [B,A]
    float* __restrict__ maxpg)              // [B*M]
{
    __shared__ float s_v[WMAX * 64];
    __shared__ float s_selv[TOPK];
    __shared__ int   s_seli[TOPK];
    __shared__ float s_keepval[TOPK];

    int bm = blockIdx.x;
    int t = threadIdx.x;
    float mgt = mg[bm];
    if (mgt <= 0.f) {
        if (t == 0) maxpg[bm] = 0.f;
        return;
    }
    float gx1 = gb[bm * 4 + 0], gy1 = gb[bm * 4 + 1];
    float gx2 = gb[bm * 4 + 2], gy2 = gb[bm * 4 + 3];
    int wy0 = max(0, (int)gy1 - 13), wy1 = min(91, (int)gy2 + 13);  // same formula as kP => subset of written rows
    int wx0 = max(0, (int)gx1 - 13), wx1 = min(91, (int)gx2 + 13);
    int nrows = wy1 - wy0 + 1, ncols = wx1 - wx0 + 1;

    const float* row = align_t + (size_t)bm * A_TOT;
    for (int r = 0; r < nrows; ++r)
        s_v[r * 64 + t] = (t < ncols) ? row[(wy0 + r) * GRID_W + wx0 + t] : -1.f;
    __syncthreads();

    // 10 exact selections; all positives of the full row live in the window, and
    // zero-valued candidates are provably dropped by the in-gt filter below.
    for (int it = 0; it < TOPK; ++it) {
        float bv = -1.f; int ba = 0x7FFFFFFF;
        for (int r = 0; r < nrows; ++r) {
            float v = s_v[r * 64 + t];
            if (v > bv) { bv = v; ba = (wy0 + r) * GRID_W + wx0 + t; }
        }
        #pragma unroll
        for (int off = 1; off < 64; off <<= 1) {
            float ov = __shfl_xor(bv, off);
            int   oa = __shfl_xor(ba, off);
            if (ov > bv || (ov == bv && oa < ba)) { bv = ov; ba = oa; }
        }
        if (t == 0) {
            s_selv[it] = bv; s_seli[it] = ba;
            int gy = div92(ba);
            int rr = gy - wy0, ll = ba - GRID_W * gy - wx0;
            s_v[rr * 64 + ll] = -1.f;
        }
        __syncthreads();
    }

    if (t < TOPK) {
        int a = s_seli[t]; float v = s_selv[t];
        int gy = div92(a), gx = a - GRID_W * gy;
        float ax = gx + 0.5f, ay = gy + 0.5f;
        float d1 = ax - gx1, d2 = ay - gy1, d3 = gx2 - ax, d4 = gy2 - ay;
        float dmin = fminf(fminf(d1, d2), fminf(d3, d4));
        bool keep = (dmin > EPSF) && (v >= 0.f);
        s_keepval[t] = keep ? v : -1.f;
        if (keep) {
            int b = bm >> 6, m = bm & 63;
            unsigned long long k = ((unsigned long long)__float_as_uint(v) << 32)
                                 | (unsigned long long)(0xFFFFu - (unsigned)m);
            atomicMax(&key[(size_t)b * A_TOT + a], k);
        }
    }
    __syncthreads();
    if (t == 0) {
        float mx = 0.f;
        for (int i = 0; i < TOPK; ++i)
            if (s_keepval[i] >= 0.f) mx = fmaxf(mx, s_keepval[i]);
        maxpg[bm] = mx;
    }
}

// ---------- kC: per-fg-anchor loss terms (unchanged, known-good) ----------
__global__ __launch_bounds__(256) void kC(
    const float* __restrict__ ps, const float* __restrict__ pd, const float* __restrict__ pb,
    const float* __restrict__ anc, const int* __restrict__ gl, const float* __restrict__ gb,
    const float* __restrict__ align_t, const unsigned long long* __restrict__ key,
    const float* __restrict__ maxpg, double* __restrict__ acc)
{
    int i = blockIdx.x * blockDim.x + threadIdx.x;
    double s1 = 0, s2 = 0, s3 = 0, s4 = 0, nf = 0;
    if (i < B_SZ * A_TOT) {
        unsigned long long k = key[i];
        if (k) {
            int b = i / A_TOT, a = i % A_TOT;
            unsigned vbits = (unsigned)(k >> 32);
            int m = vbits ? (int)(0xFFFFu - (unsigned)(k & 0xFFFFull)) : 0;
            int bm = b * M_SZ + m;
            float gx1 = gb[bm * 4 + 0], gy1 = gb[bm * 4 + 1];
            float gx2 = gb[bm * 4 + 2], gy2 = gb[bm * 4 + 3];
            int cls = min(max(gl[bm], 0), NCC - 1);
            const float* px = pb + ((size_t)b * A_TOT + a) * 4;
            float p1 = px[0], p2 = px[1], p3 = px[2], p4 = px[3];

            float av = align_t[(size_t)bm * A_TOT + a];
            float xt = ps[((size_t)b * A_TOT + a) * NCC + cls];
            float norm = av / (maxpg[bm] + EPSF);

            float iw = fmaxf(fminf(p3, gx2) - fmaxf(p1, gx1), 0.f);
            float ih = fmaxf(fminf(p4, gy2) - fmaxf(p2, gy1), 0.f);
            float inter = iw * ih;
            float a1 = (p3 - p1) * (p4 - p2);
            float a2 = (gx2 - gx1) * (gy2 - gy1);
            float iou = inter / (a1 + a2 - inter + EPSF);
            float cw = fmaxf(p3, gx2) - fminf(p1, gx1);
            float ch = fmaxf(p4, gy2) - fminf(p2, gy1);
            float c2 = cw * cw + ch * ch + EPSF;
            float dx = p1 + p3 - gx1 - gx2, dy = p2 + p4 - gy1 - gy2;
            float rho2 = (dx * dx + dy * dy) * 0.25f;
            float w1 = p3 - p1, h1 = p4 - p2;
            float w2 = gx2 - gx1, h2 = gy2 - gy1;
            float dat = atanf(w1 / (h1 + EPSF)) - atanf(w2 / (h2 + EPSF));
            const float c4pi2 = (float)(4.0 / (3.14159265358979323846 * 3.14159265358979323846));
            float v = c4pi2 * dat * dat;
            float alpha = v / (1.f - iou + v + EPSF);
            float ciou = iou - (rho2 / c2 + v * alpha);

            float ax = anc[(size_t)a * 2], ay = anc[(size_t)a * 2 + 1];
            float tv[4] = { ax - gx1, ay - gy1, gx2 - ax, gy2 - ay };
            const float* pdd = pd + ((size_t)b * A_TOT + a) * 64;
            float dfl = 0.f;
            #pragma unroll
            for (int s = 0; s < 4; ++s) {
                float tt = fminf(fmaxf(tv[s], 0.f), (float)REG_MAX - 1.f - 0.01f);
                int tl = (int)tt;
                int tr = min(tl + 1, REG_MAX - 1);
                float wl = (float)(tl + 1) - tt;
                float wr = 1.f - wl;
                const float* rowp = pdd + s * 16;
                float mx = rowp[0];
                #pragma unroll
                for (int kk = 1; kk < 16; ++kk) mx = fmaxf(mx, rowp[kk]);
                float se = 0.f;
                #pragma unroll
                for (int kk = 0; kk < 16; ++kk) se += expf(rowp[kk] - mx);
                float lse = mx + logf(se);
                dfl += (lse - rowp[tl]) * wl + (lse - rowp[tr]) * wr;
            }

            s1 = (double)norm;
            s2 = (double)xt * (double)norm;
            s3 = (double)(1.f - ciou) * (double)norm;
            s4 = (double)dfl;
            nf = 1.0;
        }
    }
    __shared__ double sred[256];
    double vals[5] = { s1, s2, s3, s4, nf };
    for (int j = 0; j < 5; ++j) {
        sred[threadIdx.x] = vals[j];
        __syncthreads();
        for (int s = 128; s > 0; s >>= 1) {
            if (threadIdx.x < s) sred[threadIdx.x] += sred[threadIdx.x + s];
            __syncthreads();
        }
        if (threadIdx.x == 0 && sred[0] != 0.0) atomicAdd(&acc[j], sred[0]);
        __syncthreads();
    }
}

// ---------- kE: combine ----------
__global__ void kE(const double* __restrict__ acc, float* __restrict__ out)
{
    double tsum = acc[0];
    double tss = tsum > 1.0 ? tsum : 1.0;
    double bce = acc[5] - acc[1];
    double loss_cls = bce / tss;
    double loss_iou = acc[2] / tss;
    double nf = acc[4];
    double loss_dfl = (nf > 0.0) ? acc[3] / fmax(4.0 * nf, 1.0) : 0.0;
    out[0] = (float)(7.5 * loss_iou + 0.5 * loss_cls + 1.5 * loss_dfl);
}

extern "C" void kernel_launch(void* const* d_in, const int* in_sizes, int n_in,
                              void* d_out, int out_size, void* d_ws, size_t ws_size,
                              hipStream_t stream)
{
    const float* ps  = (const float*)d_in[0];
    const float* pd  = (const float*)d_in[1];
    const float* pb  = (const float*)d_in[2];
    const float* anc = (const float*)d_in[3];
    const int*   gl  = (const int*)d_in[4];
    const float* gb  = (const float*)d_in[5];
    const float* mg  = (const float*)d_in[6];
    float* out = (float*)d_out;

    char* ws = (char*)d_ws;
    const size_t align_bytes = (size_t)B_SZ * M_SZ * A_TOT * sizeof(float);        // 69,337,088
    const size_t key_bytes   = (size_t)B_SZ * A_TOT * sizeof(unsigned long long);  //  2,166,784
    float*              align_t = (float*)ws;
    unsigned long long* key     = (unsigned long long*)(ws + align_bytes);
    double*             acc     = (double*)(ws + align_bytes + key_bytes);
    float*              maxpg   = (float*)(ws + align_bytes + key_bytes + 64);

    hipMemsetAsync(ws + align_bytes, 0, key_bytes + 64, stream);

    kP <<<B_SZ * NCHUNK, 256, 0, stream>>>(ps, pb, gl, gb, mg, align_t, acc);
    kA3<<<B_SZ * M_SZ,   64,  0, stream>>>(align_t, gb, mg, key, maxpg);
    kC <<<(B_SZ * A_TOT + 255) / 256, 256, 0, stream>>>(ps, pd, pb, anc, gl, gb, align_t, key, maxpg, acc);
    kE <<<1, 1, 0, stream>>>(acc, out);
}

// Round 12
// 268.152 us; speedup vs baseline: 1.7006x; 1.1861x over previous
//
#include <hip/hip_runtime.h>
#include <cstdint>
#include <cstddef>

#define EPSF 1e-7f
#define NCC 80
#define REG_MAX 16
#define TOPK 10
#define GRID_W 92
#define A_TOT (GRID_W * GRID_W)   // 8464
#define B_SZ 32
#define M_SZ 64
#define CHUNK 64
#define NCHUNK ((A_TOT + CHUNK - 1) / CHUNK)   // 133
#define WMAX 52

// exact div-by-92 for a in [0, 8464): (a*45591)>>22
__device__ __forceinline__ int div92(int a) { return (a * 45591) >> 22; }

// ---------- kP: coalesced pass over pred_scores -> {BCE sum, windowed align tensor} ----------
__global__ __launch_bounds__(256) void kP(
    const float* __restrict__ ps,   // [B,A,NC]
    const float* __restrict__ pb,   // [B,A,4]
    const int*   __restrict__ gl,   // [B,M]
    const float* __restrict__ gb,   // [B,M,4]
    const float* __restrict__ mg,   // [B,M]
    float* __restrict__ align_t,    // [B,M,A] (written only for window-row chunks)
    double* __restrict__ acc)
{
    __shared__ float  sq[CHUNK][NCC + 1];   // sigmoid values; +1 pad (column reads span all banks)
    __shared__ float  sgb[M_SZ][4];
    __shared__ float  sag[M_SZ];
    __shared__ int    scls[M_SZ];
    __shared__ int    swy[M_SZ];            // wy0 | wy1<<8 ; empty = 255|0 (never overlaps)
    __shared__ double sredw[4];

    int blk = blockIdx.x;
    int b = blk / NCHUNK;
    int chunk = blk % NCHUNK;
    int a0 = chunk * CHUNK;
    int t = threadIdx.x;

    if (t < M_SZ) {
        int bm = b * M_SZ + t;
        float4 g = *(const float4*)(gb + (size_t)bm * 4);
        sgb[t][0] = g.x; sgb[t][1] = g.y; sgb[t][2] = g.z; sgb[t][3] = g.w;
        sag[t] = (g.z - g.x) * (g.w - g.y);
        int c = gl[bm]; scls[t] = min(max(c, 0), NCC - 1);
        int y0, y1;
        if (mg[bm] > 0.f) { y0 = max(0, (int)g.y - 13); y1 = min(91, (int)g.w + 13); }
        else             { y0 = 255; y1 = 0; }         // empty window: fails cgy1>=y0 always
        swy[t] = y0 | (y1 << 8);
    }

    // stage 64 rows x 80 floats, coalesced float4; fused BCE-const sum (fast math)
    const float* base = ps + ((size_t)b * A_TOT + a0) * NCC;
    double bces = 0.0;
    #pragma unroll
    for (int k = 0; k < 5; ++k) {
        int q = t + k * 256;          // 80%4==0: no row-cross
        int r = q / 20;
        int c = (q % 20) * 4;
        if (a0 + r < A_TOT) {
            float4 v = *(const float4*)(base + (size_t)r * NCC + c);
            float bsum = 0.f;
            #pragma unroll
            for (int j = 0; j < 4; ++j) {
                float x = (&v.x)[j];
                float t1 = __expf(-fabsf(x));
                bsum += fmaxf(x, 0.f) + __logf(1.f + t1);
                float rin = __fdividef(1.f, 1.f + t1);
                sq[r][c + j] = (x >= 0.f) ? rin : t1 * rin;   // sigmoid via exp reuse
            }
            bces += (double)bsum;
        }
    }
    __syncthreads();

    int w = t >> 6, l = t & 63;
    // active-m mask via ballot: lane l evaluates m = l (all 64 lanes active here)
    int wyp = swy[l];
    int y0 = wyp & 0xFF, y1 = (wyp >> 8) & 0xFF;
    int cgy0 = a0 / GRID_W, cgy1 = (a0 + CHUNK - 1) / GRID_W;
    bool ov = (cgy0 <= y1) && (cgy1 >= y0);
    unsigned long long mask0 = __ballot(ov);
    unsigned int mask = (unsigned int)((mask0 >> (w * 16)) & 0xFFFFull);

    int a = a0 + l;
    if (a < A_TOT && mask) {
        float4 p = *(const float4*)(pb + ((size_t)b * A_TOT + a) * 4);
        float ap_area = (p.z - p.x) * (p.w - p.y);
        float* outbase = align_t + (size_t)b * M_SZ * A_TOT + a;
        while (mask) {
            int mi = __builtin_ctz(mask); mask &= mask - 1;
            int m = w * 16 + mi;
            float g1 = sgb[m][0], g2 = sgb[m][1], g3 = sgb[m][2], g4 = sgb[m][3];
            float iw = fmaxf(fminf(g3, p.z) - fmaxf(g1, p.x), 0.f);
            float ih = fmaxf(fminf(g4, p.w) - fmaxf(g2, p.y), 0.f);
            float inter = iw * ih;
            float iou = inter * __fdividef(1.f, sag[m] + ap_area - inter + EPSF);
            float s = sqrtf(sq[l][scls[m]]);
            float i2 = iou * iou;
            outbase[(size_t)m * A_TOT] = s * (i2 * i2 * i2);  // mg>0 here => mask factor == 1
        }
    }

    // wave shuffle-reduce (f64) + single barrier
    double v = bces;
    #pragma unroll
    for (int off = 1; off < 64; off <<= 1) v += __shfl_xor(v, off);
    if (l == 0) sredw[w] = v;
    __syncthreads();
    if (t == 0) atomicAdd(&acc[5], sredw[0] + sredw[1] + sredw[2] + sredw[3]);
}

// ---------- kA3: windowed exact top-10 per (b,m), one wave per block ----------
__global__ __launch_bounds__(64) void kA3(
    const float* __restrict__ align_t,
    const float* __restrict__ gb,
    const float* __restrict__ mg,
    unsigned long long* __restrict__ key,   // [B,A]
    float* __restrict__ maxpg)              // [B*M]
{
    __shared__ float s_v[WMAX * 64];
    __shared__ float s_selv[TOPK];
    __shared__ int   s_seli[TOPK];
    __shared__ float s_keepval[TOPK];

    int bm = blockIdx.x;
    int t = threadIdx.x;
    float mgt = mg[bm];
    if (mgt <= 0.f) {
        if (t == 0) maxpg[bm] = 0.f;
        return;
    }
    float gx1 = gb[bm * 4 + 0], gy1 = gb[bm * 4 + 1];
    float gx2 = gb[bm * 4 + 2], gy2 = gb[bm * 4 + 3];
    int wy0 = max(0, (int)gy1 - 13), wy1 = min(91, (int)gy2 + 13);  // same formula as kP => subset of written rows
    int wx0 = max(0, (int)gx1 - 13), wx1 = min(91, (int)gx2 + 13);
    int nrows = wy1 - wy0 + 1, ncols = wx1 - wx0 + 1;

    const float* row = align_t + (size_t)bm * A_TOT;
    #pragma unroll 4
    for (int r = 0; r < nrows; ++r)
        s_v[r * 64 + t] = (t < ncols) ? row[(wy0 + r) * GRID_W + wx0 + t] : -1.f;
    __syncthreads();

    for (int it = 0; it < TOPK; ++it) {
        float bv = -1.f; int ba = 0x7FFFFFFF;
        #pragma unroll 4
        for (int r = 0; r < nrows; ++r) {
            float v = s_v[r * 64 + t];
            if (v > bv) { bv = v; ba = (wy0 + r) * GRID_W + wx0 + t; }
        }
        #pragma unroll
        for (int off = 1; off < 64; off <<= 1) {
            float ov = __shfl_xor(bv, off);
            int   oa = __shfl_xor(ba, off);
            if (ov > bv || (ov == bv && oa < ba)) { bv = ov; ba = oa; }
        }
        if (t == 0) {
            s_selv[it] = bv; s_seli[it] = ba;
            int gy = div92(ba);
            int rr = gy - wy0, ll = ba - GRID_W * gy - wx0;
            s_v[rr * 64 + ll] = -1.f;
        }
        __syncthreads();
    }

    if (t < TOPK) {
        int a = s_seli[t]; float v = s_selv[t];
        int gy = div92(a), gx = a - GRID_W * gy;
        float ax = gx + 0.5f, ay = gy + 0.5f;
        float d1 = ax - gx1, d2 = ay - gy1, d3 = gx2 - ax, d4 = gy2 - ay;
        float dmin = fminf(fminf(d1, d2), fminf(d3, d4));
        bool keep = (dmin > EPSF) && (v >= 0.f);
        s_keepval[t] = keep ? v : -1.f;
        if (keep) {
            int b = bm >> 6, m = bm & 63;
            unsigned long long k = ((unsigned long long)__float_as_uint(v) << 32)
                                 | (unsigned long long)(0xFFFFu - (unsigned)m);
            atomicMax(&key[(size_t)b * A_TOT + a], k);
        }
    }
    __syncthreads();
    if (t == 0) {
        float mx = 0.f;
        for (int i = 0; i < TOPK; ++i)
            if (s_keepval[i] >= 0.f) mx = fmaxf(mx, s_keepval[i]);
        maxpg[bm] = mx;
    }
}

// ---------- kC: per-fg-anchor loss terms ----------
__global__ __launch_bounds__(256) void kC(
    const float* __restrict__ ps, const float* __restrict__ pd, const float* __restrict__ pb,
    const int* __restrict__ gl, const float* __restrict__ gb,
    const float* __restrict__ align_t, const unsigned long long* __restrict__ key,
    const float* __restrict__ maxpg, double* __restrict__ acc)
{
    int i = blockIdx.x * blockDim.x + threadIdx.x;
    double s1 = 0, s2 = 0, s3 = 0, s4 = 0, nf = 0;
    if (i < B_SZ * A_TOT) {
        unsigned long long k = key[i];
        if (k) {
            int b = i / A_TOT, a = i % A_TOT;
            unsigned vbits = (unsigned)(k >> 32);
            int m = vbits ? (int)(0xFFFFu - (unsigned)(k & 0xFFFFull)) : 0;
            int bm = b * M_SZ + m;
            float gx1 = gb[bm * 4 + 0], gy1 = gb[bm * 4 + 1];
            float gx2 = gb[bm * 4 + 2], gy2 = gb[bm * 4 + 3];
            int cls = min(max(gl[bm], 0), NCC - 1);
            const float* px = pb + ((size_t)b * A_TOT + a) * 4;
            float p1 = px[0], p2 = px[1], p3 = px[2], p4 = px[3];

            float av = align_t[(size_t)bm * A_TOT + a];
            float xt = ps[((size_t)b * A_TOT + a) * NCC + cls];
            float norm = av / (maxpg[bm] + EPSF);

            float iw = fmaxf(fminf(p3, gx2) - fmaxf(p1, gx1), 0.f);
            float ih = fmaxf(fminf(p4, gy2) - fmaxf(p2, gy1), 0.f);
            float inter = iw * ih;
            float a1 = (p3 - p1) * (p4 - p2);
            float a2 = (gx2 - gx1) * (gy2 - gy1);
            float iou = inter / (a1 + a2 - inter + EPSF);
            float cw = fmaxf(p3, gx2) - fminf(p1, gx1);
            float ch = fmaxf(p4, gy2) - fminf(p2, gy1);
            float c2 = cw * cw + ch * ch + EPSF;
            float dx = p1 + p3 - gx1 - gx2, dy = p2 + p4 - gy1 - gy2;
            float rho2 = (dx * dx + dy * dy) * 0.25f;
            float w1 = p3 - p1, h1 = p4 - p2;
            float w2 = gx2 - gx1, h2 = gy2 - gy1;
            float dat = atanf(w1 / (h1 + EPSF)) - atanf(w2 / (h2 + EPSF));
            const float c4pi2 = (float)(4.0 / (3.14159265358979323846 * 3.14159265358979323846));
            float v = c4pi2 * dat * dat;
            float alpha = v / (1.f - iou + v + EPSF);
            float ciou = iou - (rho2 / c2 + v * alpha);

            int gy = div92(a), gx = a - GRID_W * gy;
            float ax = gx + 0.5f, ay = gy + 0.5f;
            float tv[4] = { ax - gx1, ay - gy1, gx2 - ax, gy2 - ay };
            const float* pdd = pd + ((size_t)b * A_TOT + a) * 64;
            float dfl = 0.f;
            #pragma unroll
            for (int s = 0; s < 4; ++s) {
                float tt = fminf(fmaxf(tv[s], 0.f), (float)REG_MAX - 1.f - 0.01f);
                int tl = (int)tt;
                int tr = min(tl + 1, REG_MAX - 1);
                float wl = (float)(tl + 1) - tt;
                float wr = 1.f - wl;
                const float* rowp = pdd + s * 16;
                float mx = rowp[0];
                #pragma unroll
                for (int kk = 1; kk < 16; ++kk) mx = fmaxf(mx, rowp[kk]);
                float se = 0.f;
                #pragma unroll
                for (int kk = 0; kk < 16; ++kk) se += expf(rowp[kk] - mx);
                float lse = mx + logf(se);
                dfl += (lse - rowp[tl]) * wl + (lse - rowp[tr]) * wr;
            }

            s1 = (double)norm;
            s2 = (double)xt * (double)norm;
            s3 = (double)(1.f - ciou) * (double)norm;
            s4 = (double)dfl;
            nf = 1.0;
        }
    }

    // per-wave shuffle reduce (f64), one barrier, 5 atomics per block
    __shared__ double sw[4][5];
    int w = threadIdx.x >> 6, l = threadIdx.x & 63;
    double vals[5] = { s1, s2, s3, s4, nf };
    #pragma unroll
    for (int j = 0; j < 5; ++j) {
        double v = vals[j];
        #pragma unroll
        for (int off = 1; off < 64; off <<= 1) v += __shfl_xor(v, off);
        if (l == 0) sw[w][j] = v;
    }
    __syncthreads();
    if (threadIdx.x < 5) {
        double s = sw[0][threadIdx.x] + sw[1][threadIdx.x] + sw[2][threadIdx.x] + sw[3][threadIdx.x];
        if (s != 0.0) atomicAdd(&acc[threadIdx.x], s);
    }
}

// ---------- kE: combine ----------
__global__ void kE(const double* __restrict__ acc, float* __restrict__ out)
{
    double tsum = acc[0];
    double tss = tsum > 1.0 ? tsum : 1.0;
    double bce = acc[5] - acc[1];
    double loss_cls = bce / tss;
    double loss_iou = acc[2] / tss;
    double nf = acc[4];
    double loss_dfl = (nf > 0.0) ? acc[3] / fmax(4.0 * nf, 1.0) : 0.0;
    out[0] = (float)(7.5 * loss_iou + 0.5 * loss_cls + 1.5 * loss_dfl);
}

extern "C" void kernel_launch(void* const* d_in, const int* in_sizes, int n_in,
                              void* d_out, int out_size, void* d_ws, size_t ws_size,
                              hipStream_t stream)
{
    const float* ps  = (const float*)d_in[0];
    const float* pd  = (const float*)d_in[1];
    const float* pb  = (const float*)d_in[2];
    const int*   gl  = (const int*)d_in[4];
    const float* gb  = (const float*)d_in[5];
    const float* mg  = (const float*)d_in[6];
    float* out = (float*)d_out;

    char* ws = (char*)d_ws;
    const size_t align_bytes = (size_t)B_SZ * M_SZ * A_TOT * sizeof(float);        // 69,337,088
    const size_t key_bytes   = (size_t)B_SZ * A_TOT * sizeof(unsigned long long);  //  2,166,784
    float*              align_t = (float*)ws;
    unsigned long long* key     = (unsigned long long*)(ws + align_bytes);
    double*             acc     = (double*)(ws + align_bytes + key_bytes);
    float*              maxpg   = (float*)(ws + align_bytes + key_bytes + 64);

    hipMemsetAsync(ws + align_bytes, 0, key_bytes + 64, stream);

    kP <<<B_SZ * NCHUNK, 256, 0, stream>>>(ps, pb, gl, gb, mg, align_t, acc);
    kA3<<<B_SZ * M_SZ,   64,  0, stream>>>(align_t, gb, mg, key, maxpg);
    kC <<<(B_SZ * A_TOT + 255) / 256, 256, 0, stream>>>(ps, pd, pb, gl, gb, align_t, key, maxpg, acc);
    kE <<<1, 1, 0, stream>>>(acc, out);
}